// Round 1
// baseline (48.201 us; speedup 1.0000x reference)
//
#include <hip/hip_runtime.h>

#define N_DIM 2048
#define F_DIM 64

typedef __attribute__((ext_vector_type(4))) float  f32x4;
typedef __attribute__((ext_vector_type(8))) short  s16x8;
typedef __attribute__((ext_vector_type(8))) __bf16 bf16x8;

static __device__ __forceinline__ unsigned short f2bf(float f) {
  unsigned int u = __builtin_bit_cast(unsigned int, f);
  u += 0x7fffu + ((u >> 16) & 1u);      // RNE to bf16
  return (unsigned short)(u >> 16);
}

// Build MFMA B-fragments for v (bf16) and v^2 (bf16).
// Fragment layout for mfma_f32_16x16x32_bf16 B-operand:
//   lane l holds B[k = 8*(l/16) + j][col = l%16], j = 0..7
// Stored as [kt(64)][tile(4)][lane(64)][j(8)] ushort so the main kernel's
// per-lane load is one contiguous 16B dwordx4.
__global__ __launch_bounds__(256) void fm_prep(const float* __restrict__ v,
                                               unsigned short* __restrict__ vb,
                                               unsigned short* __restrict__ v2b) {
  const int tid = blockIdx.x * 256 + threadIdx.x;   // 0..16383
  const int fl = tid & 63;
  const int t  = (tid >> 6) & 3;
  const int kt = tid >> 8;                          // 0..63
  const int kbase = kt * 32 + ((fl >> 4) << 3);
  const int f = t * 16 + (fl & 15);
  s16x8 a, b;
#pragma unroll
  for (int j = 0; j < 8; ++j) {
    float val = v[(size_t)(kbase + j) * F_DIM + f];
    a[j] = (short)f2bf(val);
    b[j] = (short)f2bf(val * val);
  }
  *(s16x8*)(vb  + (size_t)tid * 8) = a;
  *(s16x8*)(v2b + (size_t)tid * 8) = b;
}

// Main: 1024 blocks x 256 threads. Block owns 16 rows of x; each of the 4
// waves accumulates a K-quarter (512) of both matmuls (xv, x2v2) via MFMA,
// plus the linear term in fp32. Epilogue combines waves through LDS,
// squares/reduces, and writes 16 outputs.
__global__ __launch_bounds__(256) void fm_main(const float* __restrict__ x,
                                               const float* __restrict__ w0,
                                               const float* __restrict__ w1,
                                               const unsigned short* __restrict__ vb,
                                               const unsigned short* __restrict__ v2b,
                                               float* __restrict__ out) {
  const int tid  = threadIdx.x;
  const int lane = tid & 63;
  const int w    = tid >> 6;            // wave 0..3
  const int rowbase = blockIdx.x * 16;
  const int lrow = lane & 15;           // A-frag row within tile
  const int ksub = (lane >> 4) << 3;    // k-offset within 32-chunk: 0,8,16,24

  f32x4 accv[4] = {};
  f32x4 acc2[4] = {};
  float lin = 0.0f;

  const float* xrow = x + (size_t)(rowbase + lrow) * N_DIM;
  const int kw = w * 512;               // this wave's K range

#pragma unroll 2
  for (int s = 0; s < 16; ++s) {
    const int kc = kw + s * 32 + ksub;
    f32x4 xa = *(const f32x4*)(xrow + kc);
    f32x4 xb = *(const f32x4*)(xrow + kc + 4);
    f32x4 wa = *(const f32x4*)(w1 + kc);
    f32x4 wb = *(const f32x4*)(w1 + kc + 4);
    const int ktIdx = (kw >> 5) + s;    // global 32-chunk index
    const unsigned short* vbp  = vb  + ((size_t)(ktIdx * 4) * 64 + lane) * 8;
    const unsigned short* v2bp = v2b + ((size_t)(ktIdx * 4) * 64 + lane) * 8;

    s16x8 af, a2f;
#pragma unroll
    for (int i = 0; i < 4; ++i) {
      lin += xa[i] * wa[i] + xb[i] * wb[i];
      af[i]     = (short)f2bf(xa[i]);
      af[4 + i] = (short)f2bf(xb[i]);
      a2f[i]     = (short)f2bf(xa[i] * xa[i]);
      a2f[4 + i] = (short)f2bf(xb[i] * xb[i]);
    }
    bf16x8 A  = __builtin_bit_cast(bf16x8, af);
    bf16x8 A2 = __builtin_bit_cast(bf16x8, a2f);

#pragma unroll
    for (int t = 0; t < 4; ++t) {
      bf16x8 Bv = __builtin_bit_cast(bf16x8, *(const s16x8*)(vbp  + t * 64 * 8));
      bf16x8 B2 = __builtin_bit_cast(bf16x8, *(const s16x8*)(v2bp + t * 64 * 8));
      accv[t] = __builtin_amdgcn_mfma_f32_16x16x32_bf16(A,  Bv, accv[t], 0, 0, 0);
      acc2[t] = __builtin_amdgcn_mfma_f32_16x16x32_bf16(A2, B2, acc2[t], 0, 0, 0);
    }
  }

  // lin: lanes {r, r+16, r+32, r+48} hold k-subchunk partials of row r
  lin += __shfl_xor(lin, 16);
  lin += __shfl_xor(lin, 32);

  __shared__ f32x4 accLDS[3][8][64];    // waves 1..3: [8 tiles][lane] (contiguous => conflict-free)
  __shared__ float linLDS[4][16];

  if (w > 0) {
#pragma unroll
    for (int t = 0; t < 4; ++t) {
      accLDS[w - 1][t][lane]     = accv[t];
      accLDS[w - 1][4 + t][lane] = acc2[t];
    }
  }
  if (lane < 16) linLDS[w][lane] = lin;
  __syncthreads();

  if (w == 0) {
#pragma unroll
    for (int ww = 0; ww < 3; ++ww) {
#pragma unroll
      for (int t = 0; t < 4; ++t) {
        accv[t] += accLDS[ww][t][lane];
        acc2[t] += accLDS[ww][4 + t][lane];
      }
    }
    // C/D layout: col = lane&15, row = 4*(lane>>4) + r
    float p[4];
#pragma unroll
    for (int r = 0; r < 4; ++r) {
      p[r] = 0.0f;
#pragma unroll
      for (int t = 0; t < 4; ++t)
        p[r] += accv[t][r] * accv[t][r] - acc2[t][r];
      p[r] += __shfl_xor(p[r], 1);
      p[r] += __shfl_xor(p[r], 2);
      p[r] += __shfl_xor(p[r], 4);
      p[r] += __shfl_xor(p[r], 8);
    }
    if ((lane & 15) == 0) {
      const int g = lane >> 4;
      const float w0v = w0[0];
#pragma unroll
      for (int r = 0; r < 4; ++r) {
        const int row = g * 4 + r;
        float lt = linLDS[0][row] + linLDS[1][row] + linLDS[2][row] + linLDS[3][row];
        out[rowbase + row] = w0v + lt + 0.5f * p[r];
      }
    }
  }
}

extern "C" void kernel_launch(void* const* d_in, const int* in_sizes, int n_in,
                              void* d_out, int out_size, void* d_ws, size_t ws_size,
                              hipStream_t stream) {
  const float* x  = (const float*)d_in[0];
  const float* w0 = (const float*)d_in[1];
  const float* w1 = (const float*)d_in[2];
  const float* v  = (const float*)d_in[3];
  float* out = (float*)d_out;

  unsigned short* vb  = (unsigned short*)d_ws;          // 64*4*64*8 = 131072 ushorts (256 KiB)
  unsigned short* v2b = vb + 131072;                    // another 256 KiB

  fm_prep<<<64, 256, 0, stream>>>(v, vb, v2b);
  fm_main<<<1024, 256, 0, stream>>>(x, w0, w1, vb, v2b, out);
}

// Round 2
// 42.683 us; speedup vs baseline: 1.1293x; 1.1293x over previous
//
#include <hip/hip_runtime.h>

#define N_DIM 2048
#define F_DIM 64

typedef __attribute__((ext_vector_type(4))) float  f32x4;
typedef __attribute__((ext_vector_type(8))) short  s16x8;
typedef __attribute__((ext_vector_type(8))) __bf16 bf16x8;

static __device__ __forceinline__ unsigned short f2bf(float f) {
  unsigned int u = __builtin_bit_cast(unsigned int, f);
  u += 0x7fffu + ((u >> 16) & 1u);      // RNE to bf16
  return (unsigned short)(u >> 16);
}

// Prep (grid 72):
//  blocks 0..63  — build MFMA B-fragments of bf16(v):
//    lane l holds B[k = 8*(l/16) + j][col = l%16], j=0..7, stored
//    [kt(64)][tile(4)][lane(64)][j(8)] so main's load is one dwordx4.
//  blocks 64..71 — s_half[k] = 0.5 * sum_f v[k][f]^2  (fp32, 2048 floats)
__global__ __launch_bounds__(256) void fm_prep(const float* __restrict__ v,
                                               unsigned short* __restrict__ vb,
                                               float* __restrict__ sh) {
  const int blk = blockIdx.x;
  const int tid = threadIdx.x;
  if (blk < 64) {
    const int g  = blk * 256 + tid;                 // 0..16383
    const int fl = g & 63;
    const int t  = (g >> 6) & 3;
    const int kt = g >> 8;                          // 0..63
    const int kbase = kt * 32 + ((fl >> 4) << 3);
    const int f = t * 16 + (fl & 15);
    s16x8 a;
#pragma unroll
    for (int j = 0; j < 8; ++j)
      a[j] = (short)f2bf(v[(size_t)(kbase + j) * F_DIM + f]);
    *(s16x8*)(vb + (size_t)g * 8) = a;
  } else {
    const int k = (blk - 64) * 256 + tid;           // 0..2047
    const f32x4* row = (const f32x4*)(v + (size_t)k * F_DIM);
    float s = 0.0f;
#pragma unroll
    for (int i = 0; i < 16; ++i) {
      f32x4 q = row[i];
      s += q[0]*q[0] + q[1]*q[1] + q[2]*q[2] + q[3]*q[3];
    }
    sh[k] = 0.5f * s;
  }
}

// Main: 1024 blocks x 256 threads. Block owns 16 rows; each of 4 waves
// accumulates a K-quarter (512) of the xv MFMA matmul plus the fused fp32
// scalar term  lin = x.w1 - 0.5*x^2.s .  Epilogue combines via LDS:
//   out = w0 + lin + 0.5 * sum_f (xv_f)^2
__global__ __launch_bounds__(256) void fm_main(const float* __restrict__ x,
                                               const float* __restrict__ w0,
                                               const float* __restrict__ w1,
                                               const unsigned short* __restrict__ vb,
                                               const float* __restrict__ sh,
                                               float* __restrict__ out) {
  const int tid  = threadIdx.x;
  const int lane = tid & 63;
  const int w    = tid >> 6;            // wave 0..3
  const int rowbase = blockIdx.x * 16;
  const int lrow = lane & 15;           // A-frag row within tile
  const int ksub = (lane >> 4) << 3;    // k-offset within 32-chunk: 0,8,16,24

  f32x4 accv[4] = {};
  float lin = 0.0f;

  const int kw = w * 512;               // this wave's K range
  const float* xrow = x + (size_t)(rowbase + lrow) * N_DIM + kw;
  const float* w1p  = w1 + kw;
  const float* shp  = sh + kw;
  const unsigned short* vbase = vb + ((size_t)(w * 16 * 4) * 64 + lane) * 8;

#pragma unroll 2
  for (int s = 0; s < 16; ++s) {
    const int kc = s * 32 + ksub;
    f32x4 xa = *(const f32x4*)(xrow + kc);
    f32x4 xb = *(const f32x4*)(xrow + kc + 4);
    f32x4 wa = *(const f32x4*)(w1p + kc);
    f32x4 wb = *(const f32x4*)(w1p + kc + 4);
    f32x4 sa = *(const f32x4*)(shp + kc);
    f32x4 sb = *(const f32x4*)(shp + kc + 4);
    const unsigned short* vbp = vbase + (size_t)s * 4 * 64 * 8;

    bf16x8 A;
#pragma unroll
    for (int i = 0; i < 4; ++i) {
      lin += xa[i] * wa[i] - (xa[i] * xa[i]) * sa[i];
      lin += xb[i] * wb[i] - (xb[i] * xb[i]) * sb[i];
      A[i]     = (__bf16)xa[i];
      A[4 + i] = (__bf16)xb[i];
    }

#pragma unroll
    for (int t = 0; t < 4; ++t) {
      bf16x8 Bv = __builtin_bit_cast(bf16x8, *(const s16x8*)(vbp + (size_t)t * 64 * 8));
      accv[t] = __builtin_amdgcn_mfma_f32_16x16x32_bf16(A, Bv, accv[t], 0, 0, 0);
    }
  }

  // lin: lanes {r, r+16, r+32, r+48} hold k-subchunk partials of row r
  lin += __shfl_xor(lin, 16);
  lin += __shfl_xor(lin, 32);

  __shared__ f32x4 accLDS[3][4][64];    // waves 1..3 accv (contiguous => conflict-free)
  __shared__ float linLDS[4][16];

  if (w > 0) {
#pragma unroll
    for (int t = 0; t < 4; ++t)
      accLDS[w - 1][t][lane] = accv[t];
  }
  if (lane < 16) linLDS[w][lane] = lin;
  __syncthreads();

  if (w == 0) {
#pragma unroll
    for (int ww = 0; ww < 3; ++ww)
#pragma unroll
      for (int t = 0; t < 4; ++t)
        accv[t] += accLDS[ww][t][lane];

    // C/D layout: col = lane&15, row = 4*(lane>>4) + r
    float p[4];
#pragma unroll
    for (int r = 0; r < 4; ++r) {
      p[r] = 0.0f;
#pragma unroll
      for (int t = 0; t < 4; ++t)
        p[r] += accv[t][r] * accv[t][r];
      p[r] += __shfl_xor(p[r], 1);
      p[r] += __shfl_xor(p[r], 2);
      p[r] += __shfl_xor(p[r], 4);
      p[r] += __shfl_xor(p[r], 8);
    }
    if ((lane & 15) == 0) {
      const int g = lane >> 4;
      const float w0v = w0[0];
#pragma unroll
      for (int r = 0; r < 4; ++r) {
        const int row = g * 4 + r;
        float lt = linLDS[0][row] + linLDS[1][row] + linLDS[2][row] + linLDS[3][row];
        out[rowbase + row] = w0v + lt + 0.5f * p[r];
      }
    }
  }
}

extern "C" void kernel_launch(void* const* d_in, const int* in_sizes, int n_in,
                              void* d_out, int out_size, void* d_ws, size_t ws_size,
                              hipStream_t stream) {
  const float* x  = (const float*)d_in[0];
  const float* w0 = (const float*)d_in[1];
  const float* w1 = (const float*)d_in[2];
  const float* v  = (const float*)d_in[3];
  float* out = (float*)d_out;

  unsigned short* vb = (unsigned short*)d_ws;           // 64*4*64*8 ushorts = 256 KiB
  float* sh = (float*)(vb + 131072);                    // 2048 floats = 8 KiB

  fm_prep<<<72, 256, 0, stream>>>(v, vb, sh);
  fm_main<<<1024, 256, 0, stream>>>(x, w0, w1, vb, sh, out);
}

// Round 3
// 35.425 us; speedup vs baseline: 1.3606x; 1.2049x over previous
//
#include <hip/hip_runtime.h>

#define N_DIM 2048
#define F_DIM 64

typedef __attribute__((ext_vector_type(4))) float  f32x4;
typedef __attribute__((ext_vector_type(8))) short  s16x8;
typedef __attribute__((ext_vector_type(8))) __bf16 bf16x8;

static __device__ __forceinline__ unsigned short f2bf(float f) {
  unsigned int u = __builtin_bit_cast(unsigned int, f);
  u += 0x7fffu + ((u >> 16) & 1u);      // RNE to bf16
  return (unsigned short)(u >> 16);
}

// Prep (grid 72):
//  blocks 0..63  — build MFMA B-fragments of bf16(v):
//    lane l holds B[k = 8*(l/16) + j][col = l%16], j=0..7, stored
//    [kt(64)][tile(4)][lane(64)][j(8)] so main's load is one dwordx4.
//  blocks 64..71 — s_half[k] = 0.5 * sum_f v[k][f]^2  (fp32, 2048 floats)
__global__ __launch_bounds__(256) void fm_prep(const float* __restrict__ v,
                                               unsigned short* __restrict__ vb,
                                               float* __restrict__ sh) {
  const int blk = blockIdx.x;
  const int tid = threadIdx.x;
  if (blk < 64) {
    const int g  = blk * 256 + tid;                 // 0..16383
    const int fl = g & 63;
    const int t  = (g >> 6) & 3;
    const int kt = g >> 8;                          // 0..63
    const int kbase = kt * 32 + ((fl >> 4) << 3);
    const int f = t * 16 + (fl & 15);
    s16x8 a;
#pragma unroll
    for (int j = 0; j < 8; ++j)
      a[j] = (short)f2bf(v[(size_t)(kbase + j) * F_DIM + f]);
    *(s16x8*)(vb + (size_t)g * 8) = a;
  } else {
    const int k = (blk - 64) * 256 + tid;           // 0..2047
    const f32x4* row = (const f32x4*)(v + (size_t)k * F_DIM);
    float s = 0.0f;
#pragma unroll
    for (int i = 0; i < 16; ++i) {
      f32x4 q = row[i];
      s += q[0]*q[0] + q[1]*q[1] + q[2]*q[2] + q[3]*q[3];
    }
    sh[k] = 0.5f * s;
  }
}

// Main: 1024 blocks x 256 threads. Block owns 16 rows; each of 4 waves
// accumulates a K-quarter (512) of the xv MFMA matmul plus the fused fp32
// scalar term  lin = x.w1 - 0.5*x^2.s  (w1/sh served from LDS).
// Depth-2 software pipeline on the 6 vmem loads/iter (x pair + 4 vb frags).
// Epilogue: out = w0 + lin + 0.5 * sum_f (xv_f)^2
__global__ __launch_bounds__(256) void fm_main(const float* __restrict__ x,
                                               const float* __restrict__ w0,
                                               const float* __restrict__ w1,
                                               const unsigned short* __restrict__ vb,
                                               const float* __restrict__ sh,
                                               float* __restrict__ out) {
  const int tid  = threadIdx.x;
  const int lane = tid & 63;
  const int w    = tid >> 6;            // wave 0..3
  const int rowbase = blockIdx.x * 16;
  const int lrow = lane & 15;           // A-frag row within tile
  const int ksub = (lane >> 4) << 3;    // k-offset within 32-chunk: 0,8,16,24

  __shared__ float w1L[N_DIM];          // 8 KiB
  __shared__ float shL[N_DIM];          // 8 KiB
  __shared__ f32x4 accLDS[3][4][64];    // 12 KiB, epilogue
  __shared__ float linLDS[4][16];

  const int kw = w * 512;               // this wave's K range
  const float* xrow = x + (size_t)(rowbase + lrow) * N_DIM + kw;
  const unsigned short* vbase = vb + ((size_t)(w * 64) * 64 + lane) * 8;

  // ---- prefetch slot 0 (s=0) before the staging barrier ----
  f32x4 pxa[2], pxb[2];
  s16x8 pb[2][4];
  pxa[0] = *(const f32x4*)(xrow + ksub);
  pxb[0] = *(const f32x4*)(xrow + ksub + 4);
#pragma unroll
  for (int t = 0; t < 4; ++t)
    pb[0][t] = *(const s16x8*)(vbase + t * 512);

  // ---- stage w1/sh into LDS (256 thr x 8 floats each array) ----
  {
    const int t8 = tid * 8;
    *(f32x4*)(&w1L[t8])     = *(const f32x4*)(w1 + t8);
    *(f32x4*)(&w1L[t8 + 4]) = *(const f32x4*)(w1 + t8 + 4);
    *(f32x4*)(&shL[t8])     = *(const f32x4*)(sh + t8);
    *(f32x4*)(&shL[t8 + 4]) = *(const f32x4*)(sh + t8 + 4);
  }
  __syncthreads();

  const float* w1q = w1L + kw;
  const float* shq = shL + kw;

  f32x4 accv[4] = {};
  float lin = 0.0f;

#pragma unroll
  for (int s = 0; s < 16; ++s) {
    const int cur = s & 1, nxt = cur ^ 1;
    if (s < 15) {                        // issue next iteration's 6 vmem loads
      const int kc = (s + 1) * 32 + ksub;
      pxa[nxt] = *(const f32x4*)(xrow + kc);
      pxb[nxt] = *(const f32x4*)(xrow + kc + 4);
      const unsigned short* vbp = vbase + (size_t)(s + 1) * 2048;
#pragma unroll
      for (int t = 0; t < 4; ++t)
        pb[nxt][t] = *(const s16x8*)(vbp + t * 512);
    }
    const int kc = s * 32 + ksub;
    f32x4 wa = *(const f32x4*)(w1q + kc);
    f32x4 wb = *(const f32x4*)(w1q + kc + 4);
    f32x4 sa = *(const f32x4*)(shq + kc);
    f32x4 sb = *(const f32x4*)(shq + kc + 4);
    f32x4 xa = pxa[cur], xb = pxb[cur];
    bf16x8 A;
#pragma unroll
    for (int i = 0; i < 4; ++i) {
      lin = fmaf(xa[i], wa[i] - xa[i] * sa[i], lin);
      lin = fmaf(xb[i], wb[i] - xb[i] * sb[i], lin);
      A[i]     = (__bf16)xa[i];
      A[4 + i] = (__bf16)xb[i];
    }
#pragma unroll
    for (int t = 0; t < 4; ++t)
      accv[t] = __builtin_amdgcn_mfma_f32_16x16x32_bf16(
          A, __builtin_bit_cast(bf16x8, pb[cur][t]), accv[t], 0, 0, 0);
  }

  // lin: lanes {r, r+16, r+32, r+48} hold k-subchunk partials of row r
  lin += __shfl_xor(lin, 16);
  lin += __shfl_xor(lin, 32);

  if (w > 0) {
#pragma unroll
    for (int t = 0; t < 4; ++t)
      accLDS[w - 1][t][lane] = accv[t];
  }
  if (lane < 16) linLDS[w][lane] = lin;
  __syncthreads();

  if (w == 0) {
#pragma unroll
    for (int ww = 0; ww < 3; ++ww)
#pragma unroll
      for (int t = 0; t < 4; ++t)
        accv[t] += accLDS[ww][t][lane];

    // C/D layout: col = lane&15, row = 4*(lane>>4) + r
    float p[4];
#pragma unroll
    for (int r = 0; r < 4; ++r) {
      p[r] = 0.0f;
#pragma unroll
      for (int t = 0; t < 4; ++t)
        p[r] += accv[t][r] * accv[t][r];
      p[r] += __shfl_xor(p[r], 1);
      p[r] += __shfl_xor(p[r], 2);
      p[r] += __shfl_xor(p[r], 4);
      p[r] += __shfl_xor(p[r], 8);
    }
    if ((lane & 15) == 0) {
      const int g = lane >> 4;
      const float w0v = w0[0];
#pragma unroll
      for (int r = 0; r < 4; ++r) {
        const int row = g * 4 + r;
        float lt = linLDS[0][row] + linLDS[1][row] + linLDS[2][row] + linLDS[3][row];
        out[rowbase + row] = w0v + lt + 0.5f * p[r];
      }
    }
  }
}

extern "C" void kernel_launch(void* const* d_in, const int* in_sizes, int n_in,
                              void* d_out, int out_size, void* d_ws, size_t ws_size,
                              hipStream_t stream) {
  const float* x  = (const float*)d_in[0];
  const float* w0 = (const float*)d_in[1];
  const float* w1 = (const float*)d_in[2];
  const float* v  = (const float*)d_in[3];
  float* out = (float*)d_out;

  unsigned short* vb = (unsigned short*)d_ws;           // 64*4*64*8 ushorts = 256 KiB
  float* sh = (float*)(vb + 131072);                    // 2048 floats = 8 KiB

  fm_prep<<<72, 256, 0, stream>>>(v, vb, sh);
  fm_main<<<1024, 256, 0, stream>>>(x, w0, w1, vb, sh, out);
}

// Round 4
// 35.413 us; speedup vs baseline: 1.3611x; 1.0003x over previous
//
#include <hip/hip_runtime.h>

#define N_DIM 2048
#define F_DIM 64

typedef __attribute__((ext_vector_type(4))) float  f32x4;
typedef __attribute__((ext_vector_type(8))) short  s16x8;
typedef __attribute__((ext_vector_type(8))) __bf16 bf16x8;

static __device__ __forceinline__ unsigned short f2bf(float f) {
  unsigned int u = __builtin_bit_cast(unsigned int, f);
  u += 0x7fffu + ((u >> 16) & 1u);      // RNE to bf16
  return (unsigned short)(u >> 16);
}

// Prep (grid 72):
//  blocks 0..63  — build MFMA B-fragments of bf16(v):
//    lane l holds B[k = 8*(l/16) + j][col = l%16], j=0..7, stored
//    [kt(64)][tile(4)][lane(64)][j(8)] so main's load is one dwordx4.
//  blocks 64..71 — s_half[k] = 0.5 * sum_f v[k][f]^2  (fp32, 2048 floats)
__global__ __launch_bounds__(256) void fm_prep(const float* __restrict__ v,
                                               unsigned short* __restrict__ vb,
                                               float* __restrict__ sh) {
  const int blk = blockIdx.x;
  const int tid = threadIdx.x;
  if (blk < 64) {
    const int g  = blk * 256 + tid;                 // 0..16383
    const int fl = g & 63;
    const int t  = (g >> 6) & 3;
    const int kt = g >> 8;                          // 0..63
    const int kbase = kt * 32 + ((fl >> 4) << 3);
    const int f = t * 16 + (fl & 15);
    s16x8 a;
#pragma unroll
    for (int j = 0; j < 8; ++j)
      a[j] = (short)f2bf(v[(size_t)(kbase + j) * F_DIM + f]);
    *(s16x8*)(vb + (size_t)g * 8) = a;
  } else {
    const int k = (blk - 64) * 256 + tid;           // 0..2047
    const f32x4* row = (const f32x4*)(v + (size_t)k * F_DIM);
    float s = 0.0f;
#pragma unroll
    for (int i = 0; i < 16; ++i) {
      f32x4 q = row[i];
      s += q[0]*q[0] + q[1]*q[1] + q[2]*q[2] + q[3]*q[3];
    }
    sh[k] = 0.5f * s;
  }
}

// Main: 1024 blocks x 256 threads. Block owns 16 rows; each of 4 waves
// accumulates a K-quarter (512) of the xv MFMA matmul plus the fused fp32
// scalar term  lin = x.w1 - 0.5*x^2.s  (w1/sh served from LDS).
// x prefetched at depth 4 (HBM ~900cyc), vb at depth 2 (L2 ~300cyc).
// Epilogue: out = w0 + lin + 0.5 * sum_f (xv_f)^2
__global__ __launch_bounds__(256, 4) void fm_main(const float* __restrict__ x,
                                                  const float* __restrict__ w0,
                                                  const float* __restrict__ w1,
                                                  const unsigned short* __restrict__ vb,
                                                  const float* __restrict__ sh,
                                                  float* __restrict__ out) {
  const int tid  = threadIdx.x;
  const int lane = tid & 63;
  const int w    = tid >> 6;            // wave 0..3
  const int rowbase = blockIdx.x * 16;
  const int lrow = lane & 15;           // A-frag row within tile
  const int ksub = (lane >> 4) << 3;    // k-offset within 32-chunk: 0,8,16,24

  __shared__ float w1L[N_DIM];          // 8 KiB
  __shared__ float shL[N_DIM];          // 8 KiB
  __shared__ f32x4 accLDS[3][4][64];    // 12 KiB, epilogue
  __shared__ float linLDS[4][16];

  const int kw = w * 512;               // this wave's K range
  const float* xrow = x + (size_t)(rowbase + lrow) * N_DIM + kw;
  const unsigned short* vbase = vb + ((size_t)(w * 64) * 64 + lane) * 8;

  // ---- prologue prefetch: x slots 0..2, vb slot 0 ----
  f32x4 pxa[4], pxb[4];
  s16x8 pb[2][4];
#pragma unroll
  for (int s = 0; s < 3; ++s) {
    const int kc = s * 32 + ksub;
    pxa[s] = *(const f32x4*)(xrow + kc);
    pxb[s] = *(const f32x4*)(xrow + kc + 4);
  }
#pragma unroll
  for (int t = 0; t < 4; ++t)
    pb[0][t] = *(const s16x8*)(vbase + t * 512);

  // ---- stage w1/sh into LDS (256 thr x 8 floats each array) ----
  {
    const int t8 = tid * 8;
    *(f32x4*)(&w1L[t8])     = *(const f32x4*)(w1 + t8);
    *(f32x4*)(&w1L[t8 + 4]) = *(const f32x4*)(w1 + t8 + 4);
    *(f32x4*)(&shL[t8])     = *(const f32x4*)(sh + t8);
    *(f32x4*)(&shL[t8 + 4]) = *(const f32x4*)(sh + t8 + 4);
  }
  __syncthreads();

  const float* w1q = w1L + kw;
  const float* shq = shL + kw;

  f32x4 accv[4] = {};
  float lin = 0.0f;

#pragma unroll
  for (int s = 0; s < 16; ++s) {
    // issue x loads 3 iterations ahead
    if (s < 13) {
      const int kc = (s + 3) * 32 + ksub;
      pxa[(s + 3) & 3] = *(const f32x4*)(xrow + kc);
      pxb[(s + 3) & 3] = *(const f32x4*)(xrow + kc + 4);
    }
    // issue vb loads 1 iteration ahead
    if (s < 15) {
      const unsigned short* vbp = vbase + (size_t)(s + 1) * 2048;
#pragma unroll
      for (int t = 0; t < 4; ++t)
        pb[(s + 1) & 1][t] = *(const s16x8*)(vbp + t * 512);
    }
    const int kc = s * 32 + ksub;
    f32x4 wa = *(const f32x4*)(w1q + kc);
    f32x4 wb = *(const f32x4*)(w1q + kc + 4);
    f32x4 sa = *(const f32x4*)(shq + kc);
    f32x4 sb = *(const f32x4*)(shq + kc + 4);
    f32x4 xa = pxa[s & 3], xb = pxb[s & 3];
    bf16x8 A;
#pragma unroll
    for (int i = 0; i < 4; ++i) {
      lin = fmaf(xa[i], wa[i] - xa[i] * sa[i], lin);
      lin = fmaf(xb[i], wb[i] - xb[i] * sb[i], lin);
      A[i]     = (__bf16)xa[i];
      A[4 + i] = (__bf16)xb[i];
    }
#pragma unroll
    for (int t = 0; t < 4; ++t)
      accv[t] = __builtin_amdgcn_mfma_f32_16x16x32_bf16(
          A, __builtin_bit_cast(bf16x8, pb[s & 1][t]), accv[t], 0, 0, 0);
  }

  // lin: lanes {r, r+16, r+32, r+48} hold k-subchunk partials of row r
  lin += __shfl_xor(lin, 16);
  lin += __shfl_xor(lin, 32);

  if (w > 0) {
#pragma unroll
    for (int t = 0; t < 4; ++t)
      accLDS[w - 1][t][lane] = accv[t];
  }
  if (lane < 16) linLDS[w][lane] = lin;
  __syncthreads();

  if (w == 0) {
#pragma unroll
    for (int ww = 0; ww < 3; ++ww)
#pragma unroll
      for (int t = 0; t < 4; ++t)
        accv[t] += accLDS[ww][t][lane];

    // C/D layout: col = lane&15, row = 4*(lane>>4) + r
    float p[4];
#pragma unroll
    for (int r = 0; r < 4; ++r) {
      p[r] = 0.0f;
#pragma unroll
      for (int t = 0; t < 4; ++t)
        p[r] += accv[t][r] * accv[t][r];
      p[r] += __shfl_xor(p[r], 1);
      p[r] += __shfl_xor(p[r], 2);
      p[r] += __shfl_xor(p[r], 4);
      p[r] += __shfl_xor(p[r], 8);
    }
    if ((lane & 15) == 0) {
      const int g = lane >> 4;
      const float w0v = w0[0];
#pragma unroll
      for (int r = 0; r < 4; ++r) {
        const int row = g * 4 + r;
        float lt = linLDS[0][row] + linLDS[1][row] + linLDS[2][row] + linLDS[3][row];
        out[rowbase + row] = w0v + lt + 0.5f * p[r];
      }
    }
  }
}

extern "C" void kernel_launch(void* const* d_in, const int* in_sizes, int n_in,
                              void* d_out, int out_size, void* d_ws, size_t ws_size,
                              hipStream_t stream) {
  const float* x  = (const float*)d_in[0];
  const float* w0 = (const float*)d_in[1];
  const float* w1 = (const float*)d_in[2];
  const float* v  = (const float*)d_in[3];
  float* out = (float*)d_out;

  unsigned short* vb = (unsigned short*)d_ws;           // 64*4*64*8 ushorts = 256 KiB
  float* sh = (float*)(vb + 131072);                    // 2048 floats = 8 KiB

  fm_prep<<<72, 256, 0, stream>>>(v, vb, sh);
  fm_main<<<1024, 256, 0, stream>>>(x, w0, w1, vb, sh, out);
}